// Round 2
// baseline (568.471 us; speedup 1.0000x reference)
//
#include <hip/hip_runtime.h>

// Self-attention, B=4, N=4096, D=256 (single head over full D).
//   Q = x Wq^T + bq ; K,V likewise ; S = Q K^T ; mask==0 -> -inf ;
//   attn = softmax(S/16) ; out = attn V        (fp32 in/out)
// Plan:
//   k0: convert Wq/Wk/Wv fp32 -> bf16 (ws)
//   k1: QKV projection (bf16 MFMA). Q pre-scaled by log2(e)/16 (folds the
//       1/sqrt(D) softmax scale AND base-2 exp into Q). V stored transposed
//       + tiled [b][ntile][256 d][64 n] so PV B-frags are contiguous 16B.
//   k2: flash attention. 256 WGs (1/CU), 4 waves, M=64 q rows per WG, full
//       Q in registers, Nk=64 K-tiles, online softmax (base-2), row-sums
//       via MFMA x ones-frag, P transposes C-layout->A-layout through LDS.
// ws layout: Qs bf16 8MiB | Kb bf16 8MiB | Vt bf16 8MiB | Wb bf16 384KiB

#define DEV static __device__ __forceinline__

typedef __attribute__((ext_vector_type(8))) short bf8;   // 8 bf16 (4 VGPR)
typedef __attribute__((ext_vector_type(4))) short sh4;
typedef __attribute__((ext_vector_type(4))) float f4;

DEV short f2bf(float x) {  // fp32 -> bf16 RNE (inputs finite)
  unsigned u = __builtin_bit_cast(unsigned, x);
  u += 0x7FFFu + ((u >> 16) & 1u);
  return (short)(u >> 16);
}

DEV bf8 cvt8(f4 a, f4 b) {
  bf8 r;
  r[0] = f2bf(a[0]); r[1] = f2bf(a[1]); r[2] = f2bf(a[2]); r[3] = f2bf(a[3]);
  r[4] = f2bf(b[0]); r[5] = f2bf(b[1]); r[6] = f2bf(b[2]); r[7] = f2bf(b[3]);
  return r;
}

DEV f4 mfma16(bf8 a, bf8 b, f4 c) {
  return __builtin_amdgcn_mfma_f32_16x16x32_bf16(a, b, c, 0, 0, 0);
}

// ---------------- kernel 0: W fp32 -> bf16 ----------------
__global__ void wconv(const float* __restrict__ Wq, const float* __restrict__ Wk,
                      const float* __restrict__ Wv, short* __restrict__ Wb) {
  int idx = blockIdx.x * 1024 + threadIdx.x * 4;   // 192 blocks * 1024 = 196608
  const float* src = (idx < 65536) ? Wq : (idx < 131072) ? Wk : Wv;
  f4 f = *(const f4*)(src + (idx & 65535));
  sh4 o;
  o[0] = f2bf(f[0]); o[1] = f2bf(f[1]); o[2] = f2bf(f[2]); o[3] = f2bf(f[3]);
  *(sh4*)(Wb + idx) = o;
}

// ---------------- kernel 1: QKV projection ----------------
// grid (256, 3): x=row-block of 64, y=which (0=Q,1=K,2=V). 256 thr = 4 waves.
// Wave w owns out-cols [w*64, w*64+64): per ks loads 4 A (x, inline cvt) +
// 4 B (Wb) frags, 16 MFMAs. Dict layout: B[k=d][n=e] = W[e][d] (row-major W).
__launch_bounds__(256, 2)
__global__ void qkv(const float* __restrict__ x, const short* __restrict__ Wb,
                    const float* __restrict__ bq, const float* __restrict__ bk,
                    const float* __restrict__ bv, short* __restrict__ Qs,
                    short* __restrict__ Kb, short* __restrict__ Vt) {
  __shared__ short Vlds[256 * 72];  // V transpose staging, +8 pad vs 64
  const int which = blockIdx.y;
  const int m0 = blockIdx.x * 64;
  const int tid = threadIdx.x;
  const int w = tid >> 6, lane = tid & 63, quad = lane >> 4, c = lane & 15;
  const short* W = Wb + which * 65536;
  const float* bias = (which == 0) ? bq : (which == 1) ? bk : bv;

  f4 acc[4][4];
  const f4 z = {0.f, 0.f, 0.f, 0.f};
#pragma unroll
  for (int i = 0; i < 4; i++)
#pragma unroll
    for (int j = 0; j < 4; j++) acc[i][j] = z;

#pragma unroll
  for (int ks = 0; ks < 8; ks++) {
    bf8 a[4], b[4];
#pragma unroll
    for (int ms = 0; ms < 4; ms++) {  // A[m=lane&15][k=quad*8+j], k contiguous
      const float* xp = x + (m0 + ms * 16 + c) * 256 + ks * 32 + quad * 8;
      f4 f0 = *(const f4*)xp;
      f4 f1 = *(const f4*)(xp + 4);
      a[ms] = cvt8(f0, f1);
    }
#pragma unroll
    for (int e = 0; e < 4; e++)
      b[e] = *(const bf8*)(W + ((w * 4 + e) * 16 + c) * 256 + ks * 32 + quad * 8);
#pragma unroll
    for (int ms = 0; ms < 4; ms++)
#pragma unroll
      for (int e = 0; e < 4; e++) acc[ms][e] = mfma16(a[ms], b[e], acc[ms][e]);
  }

  float bb[4];
#pragma unroll
  for (int e = 0; e < 4; e++) bb[e] = bias[(w * 4 + e) * 16 + c];
  // Q folds softmax scale + base-2: log2(e)/sqrt(D) = 1.4426950408889634/16
  const float sc = (which == 0) ? 0.09016844005556021f : 1.0f;

  if (which < 2) {
    short* dst = (which == 0) ? Qs : Kb;
#pragma unroll
    for (int ms = 0; ms < 4; ms++)
#pragma unroll
      for (int e = 0; e < 4; e++)
#pragma unroll
        for (int r = 0; r < 4; r++)  // C/D: col=lane&15, row=quad*4+reg
          dst[(m0 + ms * 16 + quad * 4 + r) * 256 + (w * 4 + e) * 16 + c] =
              f2bf((acc[ms][e][r] + bb[e]) * sc);
  } else {
    // V: transpose through LDS, emit tiled [tt][256 d][64 n]
#pragma unroll
    for (int ms = 0; ms < 4; ms++)
#pragma unroll
      for (int e = 0; e < 4; e++)
#pragma unroll
        for (int r = 0; r < 4; r++)
          Vlds[((w * 4 + e) * 16 + c) * 72 + ms * 16 + quad * 4 + r] =
              f2bf(acc[ms][e][r] + bb[e]);
    __syncthreads();
    const int tt = m0 >> 6;
#pragma unroll
    for (int k2 = 0; k2 < 8; k2++) {
      int eidx = k2 * 2048 + tid * 8;
      *(bf8*)(Vt + tt * 16384 + eidx) =
          *(const bf8*)&Vlds[(eidx >> 6) * 72 + (eidx & 63)];
    }
  }
}

// ---------------- kernel 2: flash attention ----------------
// 256 WGs = 1/CU. batch = bx&3 so each XCD (round-robin %8) sees one batch's
// K+V (4MB = its L2). 4 waves: wave w owns n-strip [n0+w*16, +16) for S and
// d-strip [w*64, +64) for PV -> K and V frags have no cross-wave reuse, so
// they load straight from global (L2); only P round-trips through LDS.
__launch_bounds__(256, 1)
__global__ void flash(const short* __restrict__ Qs, const short* __restrict__ Kb,
                      const short* __restrict__ Vt, const int* __restrict__ mask,
                      float* __restrict__ out) {
  __shared__ short Plds[64 * 72];  // P tile, padded 64->72 (bank spread)
  __shared__ float smax[64 * 4];   // per-wave partial row maxes
  __shared__ float mrow[64];       // finalized running row max
  const int bx = blockIdx.x;
  const int batch = bx & 3;
  const int q0 = (bx >> 2) * 64;
  const int tid = threadIdx.x;
  const int w = tid >> 6, lane = tid & 63, quad = lane >> 4, c = lane & 15;

  // Q fragments: all 64 rows, resident (4 msub x 8 ks = 128 VGPR)
  bf8 aq[4][8];
  const short* qb = Qs + (batch * 4096 + q0) * 256;
#pragma unroll
  for (int ms = 0; ms < 4; ms++)
#pragma unroll
    for (int ks = 0; ks < 8; ks++)
      aq[ms][ks] = *(const bf8*)(qb + (ms * 16 + c) * 256 + ks * 32 + quad * 8);

  const f4 z = {0.f, 0.f, 0.f, 0.f};
  const f4 ninf = {-INFINITY, -INFINITY, -INFINITY, -INFINITY};
  f4 accO[4][4], lacc[4], mr[4];
#pragma unroll
  for (int ms = 0; ms < 4; ms++) {
    lacc[ms] = z;
    mr[ms] = ninf;
#pragma unroll
    for (int ds = 0; ds < 4; ds++) accO[ms][ds] = z;
  }
  const short* kb = Kb + batch * 4096 * 256;
  const short* vb = Vt + batch * 1048576;
  const int* mb = mask + batch * 16777216;
  const bf8 ONES = {0x3F80, 0x3F80, 0x3F80, 0x3F80, 0x3F80, 0x3F80, 0x3F80, 0x3F80};
  float mlin = -INFINITY;  // wave0 running max, linear (lane=row) mapping

  int mc[16], mnx[16];  // mask tile, software-pipelined 1 tile ahead
#pragma unroll
  for (int ms = 0; ms < 4; ms++)
#pragma unroll
    for (int r = 0; r < 4; r++)
      mc[ms * 4 + r] = mb[(q0 + ms * 16 + quad * 4 + r) * 4096 + w * 16 + c];

  for (int t = 0; t < 64; t++) {
    const int n0 = t * 64;
    // ---- issue global loads for this tile (K, V) + mask for t+1 ----
    bf8 bk_[8];
#pragma unroll
    for (int ks = 0; ks < 8; ks++)  // B[k][n]=K[n][k]: 16B contiguous
      bk_[ks] = *(const bf8*)(kb + (n0 + w * 16 + c) * 256 + ks * 32 + quad * 8);
    bf8 bv_[2][4];
#pragma unroll
    for (int k2 = 0; k2 < 2; k2++)
#pragma unroll
      for (int ds = 0; ds < 4; ds++)
        bv_[k2][ds] = *(const bf8*)(vb + t * 16384 + (w * 64 + ds * 16 + c) * 64 +
                                    k2 * 32 + quad * 8);
    const int tn = (t < 63) ? t + 1 : 63;
#pragma unroll
    for (int ms = 0; ms < 4; ms++)
#pragma unroll
      for (int r = 0; r < 4; r++)
        mnx[ms * 4 + r] =
            mb[(q0 + ms * 16 + quad * 4 + r) * 4096 + tn * 64 + w * 16 + c];

    // ---- S = Q' K^T (wave computes 64m x 16n strip) ----
    f4 s[4];
#pragma unroll
    for (int ms = 0; ms < 4; ms++) s[ms] = z;
#pragma unroll
    for (int ks = 0; ks < 8; ks++)
#pragma unroll
      for (int ms = 0; ms < 4; ms++) s[ms] = mfma16(aq[ms][ks], bk_[ks], s[ms]);

    // mask fill (-inf survives the folded positive scale)
#pragma unroll
    for (int ms = 0; ms < 4; ms++)
#pragma unroll
      for (int r = 0; r < 4; r++)
        s[ms][r] = (mc[ms * 4 + r] != 0) ? s[ms][r] : -INFINITY;

    // ---- per-wave partial row max over this wave's 16 cols ----
    f4 pm[4];
#pragma unroll
    for (int ms = 0; ms < 4; ms++) {
      f4 v = s[ms];
#pragma unroll
      for (int off = 1; off < 16; off <<= 1)
#pragma unroll
        for (int r = 0; r < 4; r++) v[r] = fmaxf(v[r], __shfl_xor(v[r], off, 64));
      pm[ms] = v;
    }
    {  // lane quad*16+i writes row quad*4 + (i&3) + (i>>2)*16
      const int i = c, ms2 = i >> 2, r2 = i & 3;
      f4 t01 = (ms2 & 1) ? pm[1] : pm[0];
      f4 t23 = (ms2 & 1) ? pm[3] : pm[2];
      f4 tv = (ms2 & 2) ? t23 : t01;
      float v01 = (r2 & 1) ? tv[1] : tv[0];
      float v23 = (r2 & 1) ? tv[3] : tv[2];
      float val = (r2 & 2) ? v23 : v01;
      smax[(quad * 4 + r2 + ms2 * 16) * 4 + w] = val;
    }
    __syncthreads();  // #1: smax visible
    if (w == 0) {     // finalize running max, linear row=lane
      f4 sm = *(const f4*)&smax[lane * 4];
      float mt = fmaxf(fmaxf(sm[0], sm[1]), fmaxf(sm[2], sm[3]));
      mlin = fmaxf(mlin, mt);
      mrow[lane] = mlin;
    }
    __syncthreads();  // #2: mrow visible

    // ---- alpha / rescale / P = exp2(S - m) ----
    f4 mn4[4], al[4];
#pragma unroll
    for (int ms = 0; ms < 4; ms++) {
      mn4[ms] = *(const f4*)&mrow[ms * 16 + quad * 4];
#pragma unroll
      for (int r = 0; r < 4; r++)
        al[ms][r] = __builtin_amdgcn_exp2f(mr[ms][r] - mn4[ms][r]);
      mr[ms] = mn4[ms];
      lacc[ms] *= al[ms];
#pragma unroll
      for (int ds = 0; ds < 4; ds++) accO[ms][ds] *= al[ms];
    }
#pragma unroll
    for (int ms = 0; ms < 4; ms++)
#pragma unroll
      for (int r = 0; r < 4; r++) {
        float p = __builtin_amdgcn_exp2f(s[ms][r] - mn4[ms][r]);
        Plds[(ms * 16 + quad * 4 + r) * 72 + w * 16 + c] = f2bf(p);
      }
    __syncthreads();  // #3: P visible

    // ---- O += P V (wave owns d-strip); row-sum via ones-frag MFMA ----
#pragma unroll
    for (int k2 = 0; k2 < 2; k2++) {
      bf8 ap[4];
#pragma unroll
      for (int ms = 0; ms < 4; ms++)  // A[m=lane&15][k=quad*8+j]
        ap[ms] = *(const bf8*)&Plds[(ms * 16 + c) * 72 + k2 * 32 + quad * 8];
#pragma unroll
      for (int ms = 0; ms < 4; ms++) {
        lacc[ms] = mfma16(ap[ms], ONES, lacc[ms]);
#pragma unroll
        for (int ds = 0; ds < 4; ds++)
          accO[ms][ds] = mfma16(ap[ms], bv_[k2][ds], accO[ms][ds]);
      }
    }
#pragma unroll
    for (int i2 = 0; i2 < 16; i2++) mc[i2] = mnx[i2];
  }

  // ---- epilogue: O / l ----
  float* ob = out + (batch * 4096 + q0) * 256;
#pragma unroll
  for (int ms = 0; ms < 4; ms++) {
    f4 rl;
#pragma unroll
    for (int r = 0; r < 4; r++) rl[r] = __builtin_amdgcn_rcpf(lacc[ms][r]);
#pragma unroll
    for (int ds = 0; ds < 4; ds++)
#pragma unroll
      for (int r = 0; r < 4; r++)
        ob[(ms * 16 + quad * 4 + r) * 256 + w * 64 + ds * 16 + c] =
            accO[ms][ds][r] * rl[r];
  }
}

extern "C" void kernel_launch(void* const* d_in, const int* in_sizes, int n_in,
                              void* d_out, int out_size, void* d_ws, size_t ws_size,
                              hipStream_t stream) {
  const float* x = (const float*)d_in[0];
  const int* mask = (const int*)d_in[1];
  const float* Wq = (const float*)d_in[2];
  const float* bq = (const float*)d_in[3];
  const float* Wk = (const float*)d_in[4];
  const float* bk = (const float*)d_in[5];
  const float* Wv = (const float*)d_in[6];
  const float* bv = (const float*)d_in[7];
  float* out = (float*)d_out;

  char* ws = (char*)d_ws;  // needs 24MiB + 384KiB
  short* Qs = (short*)ws;
  short* Kb = (short*)(ws + (8u << 20));
  short* Vt = (short*)(ws + (16u << 20));
  short* Wb = (short*)(ws + (24u << 20));

  wconv<<<192, 256, 0, stream>>>(Wq, Wk, Wv, Wb);
  qkv<<<dim3(256, 3), 256, 0, stream>>>(x, Wb, bq, bk, bv, Qs, Kb, Vt);
  flash<<<256, 256, 0, stream>>>(Qs, Kb, Vt, mask, out);
}